// Round 1
// baseline (910.371 us; speedup 1.0000x reference)
//
#include <hip/hip_runtime.h>
#include <hip/hip_bf16.h>
#include <cstdint>

#define HID 128
#define NT 128
#define KC 32
#define SCAN_CHUNK 2048

// W tile index with interleaved pad: row stride 140 words, +4 words every 32
// -> b128 reads of d0 in {0,8,...,120} hit each 4-bank group at most 2x (free).
__device__ __forceinline__ int wt_idx(int kk, int d) {
    return kk * 140 + d + ((d >> 5) << 2);
}

// ---------------- embedding gather ----------------
__global__ void k_embed(const int* __restrict__ z, const float* __restrict__ z_emb,
                        float* __restrict__ x, int n_nodes) {
    int idx = blockIdx.x * blockDim.x + threadIdx.x;
    int total = n_nodes * (HID / 4);
    if (idx >= total) return;
    int node = idx >> 5;  // HID/4 = 32 float4 per row
    int j = idx & 31;
    ((float4*)x)[idx] = ((const float4*)z_emb)[(size_t)z[node] * 32 + j];
}

// ---------------- degree count ----------------
__global__ void k_count(const int* __restrict__ dst, int* __restrict__ deg, int n_edges) {
    int e = blockIdx.x * blockDim.x + threadIdx.x;
    if (e < n_edges) atomicAdd(&deg[dst[e]], 1);
}

// ---------------- 3-pass exclusive scan of degrees -> rowptr ----------------
__global__ void k_scan1(const int* __restrict__ deg, int* __restrict__ partials, int n) {
    __shared__ int sm[256];
    int t = threadIdx.x;
    int base = blockIdx.x * SCAN_CHUNK + t * 8;
    int s = 0;
#pragma unroll
    for (int j = 0; j < 8; ++j) { int i = base + j; if (i < n) s += deg[i]; }
    sm[t] = s;
    __syncthreads();
    for (int off = 128; off > 0; off >>= 1) {
        if (t < off) sm[t] += sm[t + off];
        __syncthreads();
    }
    if (t == 0) partials[blockIdx.x] = sm[0];
}

__global__ void k_scan2(int* partials, int nchunks) {
    int lane = threadIdx.x;  // blockDim = 64, nchunks <= 64
    int v = (lane < nchunks) ? partials[lane] : 0;
#pragma unroll
    for (int off = 1; off < 64; off <<= 1) {
        int u = __shfl_up(v, off);
        if (lane >= off) v += u;
    }
    int ex = __shfl_up(v, 1);
    if (lane == 0) ex = 0;
    if (lane < nchunks) partials[lane] = ex;
}

__global__ void k_scan3(const int* __restrict__ deg, const int* __restrict__ partials,
                        int* __restrict__ rowptr, float* __restrict__ deg_inv, int n) {
    __shared__ int wtot[4];
    int t = threadIdx.x;
    int lane = t & 63, wv = t >> 6;
    int base = blockIdx.x * SCAN_CHUNK + t * 8;
    int v[8];
    int ts = 0;
#pragma unroll
    for (int j = 0; j < 8; ++j) { int i = base + j; v[j] = (i < n) ? deg[i] : 0; ts += v[j]; }
    int incl = ts;
#pragma unroll
    for (int off = 1; off < 64; off <<= 1) {
        int u = __shfl_up(incl, off);
        if (lane >= off) incl += u;
    }
    if (lane == 63) wtot[wv] = incl;
    __syncthreads();
    int woff = 0;
    for (int w = 0; w < wv; ++w) woff += wtot[w];
    int run = partials[blockIdx.x] + woff + (incl - ts);
#pragma unroll
    for (int j = 0; j < 8; ++j) {
        int i = base + j;
        run += v[j];
        if (i < n) {
            rowptr[i + 1] = run;
            deg_inv[i] = 1.0f / fmaxf((float)v[j], 1.0f);
        }
    }
    if (blockIdx.x == 0 && t == 0) rowptr[0] = 0;
}

// ---------------- CSR fill ----------------
__global__ void k_fill(const int* __restrict__ src, const int* __restrict__ dst,
                       const int* __restrict__ rowptr, int* __restrict__ cursor,
                       int* __restrict__ csr_src, int n_edges) {
    int e = blockIdx.x * blockDim.x + threadIdx.x;
    if (e >= n_edges) return;
    int d = dst[e];
    int pos = atomicAdd(&cursor[d], 1);
    csr_src[rowptr[d] + pos] = src[e];
}

// ---------------- mean aggregation: one wave per node ----------------
__global__ void k_agg(const float* __restrict__ x, float* __restrict__ agg,
                      const int* __restrict__ rowptr, const int* __restrict__ csr_src,
                      const float* __restrict__ deg_inv, int n_nodes) {
    int wid = (blockIdx.x * blockDim.x + threadIdx.x) >> 6;
    int lane = threadIdx.x & 63;
    if (wid >= n_nodes) return;
    int s = rowptr[wid], e = rowptr[wid + 1];
    const float2* xv = (const float2*)x;
    float ax = 0.f, ay = 0.f, bx = 0.f, by = 0.f;
    int i = s;
    for (; i + 1 < e; i += 2) {  // 2-way unroll -> 2 loads in flight
        int s0 = csr_src[i], s1 = csr_src[i + 1];
        float2 v0 = xv[(size_t)s0 * 64 + lane];
        float2 v1 = xv[(size_t)s1 * 64 + lane];
        ax += v0.x; ay += v0.y; bx += v1.x; by += v1.y;
    }
    if (i < e) {
        int s0 = csr_src[i];
        float2 v0 = xv[(size_t)s0 * 64 + lane];
        ax += v0.x; ay += v0.y;
    }
    float di = deg_inv[wid];
    float2 o;
    o.x = (ax + bx) * di;
    o.y = (ay + by) * di;
    ((float2*)agg)[(size_t)wid * 64 + lane] = o;
}

// ---------------- pre-transpose [Wl|Wr] -> wcatT[layer][k=256][d=128] ----------------
__global__ void k_wt(const float* __restrict__ Wl, const float* __restrict__ Wr,
                     float* __restrict__ wcatT) {
    int idx = blockIdx.x * blockDim.x + threadIdx.x;
    if (idx >= 3 * 2 * HID * HID) return;
    int l = idx / (2 * HID * HID);
    int r = idx - l * 2 * HID * HID;
    int k = r / HID;
    int d = r - k * HID;
    float v = (k < HID) ? Wl[(size_t)l * HID * HID + (size_t)d * HID + k]
                        : Wr[(size_t)l * HID * HID + (size_t)d * HID + (k - HID)];
    wcatT[idx] = v;
}

// ---------------- fused layer GEMM: x = relu?([agg|x] @ WcatT + b), in place ----------------
__global__ __launch_bounds__(256) void k_gemm(const float* __restrict__ agg,
                                              float* __restrict__ x,
                                              const float* __restrict__ wcatT_l,
                                              const float* __restrict__ bias,
                                              int n_nodes, int do_relu) {
    __shared__ float s_in[KC * 132];  // transposed input chunk [k][node], pad 132
    __shared__ float s_w[KC * 140];   // W chunk [k][d] with interleave pad
    int t = threadIdx.x;
    int node0 = blockIdx.x * NT;
    int dg = t & 15, ng = t >> 4;
    int d0 = dg * 8, n0 = ng * 8;
    float acc[8][8];
#pragma unroll
    for (int i = 0; i < 8; ++i)
#pragma unroll
        for (int j = 0; j < 8; ++j) acc[i][j] = 0.f;

    int n_st = t & (NT - 1);
    int kh = t >> 7;  // 0..1 (which k-half of the chunk this thread stages)

    for (int kc = 0; kc < 8; ++kc) {
        const float* srcp = (kc < 4) ? agg : x;
        int ksrc = (kc & 3) * KC;
        // stage input (transpose in LDS)
        {
            int node = node0 + n_st;
            if (node < n_nodes) {
                const float4* row = (const float4*)(srcp + (size_t)node * HID + ksrc + kh * 16);
#pragma unroll
                for (int j = 0; j < 4; ++j) {
                    float4 v = row[j];
                    int k = kh * 16 + j * 4;
                    s_in[(k + 0) * 132 + n_st] = v.x;
                    s_in[(k + 1) * 132 + n_st] = v.y;
                    s_in[(k + 2) * 132 + n_st] = v.z;
                    s_in[(k + 3) * 132 + n_st] = v.w;
                }
            } else {
#pragma unroll
                for (int j = 0; j < 4; ++j) {
                    int k = kh * 16 + j * 4;
                    s_in[(k + 0) * 132 + n_st] = 0.f;
                    s_in[(k + 1) * 132 + n_st] = 0.f;
                    s_in[(k + 2) * 132 + n_st] = 0.f;
                    s_in[(k + 3) * 132 + n_st] = 0.f;
                }
            }
        }
        // stage W chunk
        {
            int kk = t >> 3;
            int dd = (t & 7) * 16;
            const float4* wrow = (const float4*)(wcatT_l + (size_t)(kc * KC + kk) * HID + dd);
#pragma unroll
            for (int j = 0; j < 4; ++j) {
                float4 w = wrow[j];
                int d = dd + j * 4;
                *(float4*)&s_w[wt_idx(kk, d)] = w;
            }
        }
        __syncthreads();
#pragma unroll 4
        for (int kk = 0; kk < KC; ++kk) {
            float4 a0 = *(const float4*)&s_in[kk * 132 + n0];
            float4 a1 = *(const float4*)&s_in[kk * 132 + n0 + 4];
            float4 w0 = *(const float4*)&s_w[wt_idx(kk, d0)];
            float4 w1 = *(const float4*)&s_w[wt_idx(kk, d0 + 4)];
            float a[8] = {a0.x, a0.y, a0.z, a0.w, a1.x, a1.y, a1.z, a1.w};
            float w[8] = {w0.x, w0.y, w0.z, w0.w, w1.x, w1.y, w1.z, w1.w};
#pragma unroll
            for (int i = 0; i < 8; ++i)
#pragma unroll
                for (int j = 0; j < 8; ++j) acc[i][j] += a[i] * w[j];
        }
        __syncthreads();
    }

    float4 b0 = *(const float4*)(bias + d0);
    float4 b1 = *(const float4*)(bias + d0 + 4);
    float bb[8] = {b0.x, b0.y, b0.z, b0.w, b1.x, b1.y, b1.z, b1.w};
#pragma unroll
    for (int i = 0; i < 8; ++i) {
        int node = node0 + n0 + i;
        if (node < n_nodes) {
            float o[8];
#pragma unroll
            for (int j = 0; j < 8; ++j) {
                float v = acc[i][j] + bb[j];
                o[j] = do_relu ? fmaxf(v, 0.f) : v;
            }
            float4* outp = (float4*)(x + (size_t)node * HID + d0);
            outp[0] = make_float4(o[0], o[1], o[2], o[3]);
            outp[1] = make_float4(o[4], o[5], o[6], o[7]);
        }
    }
}

// ---------------- center = lower_bound(batch, g) ----------------
__global__ void k_center(const int* __restrict__ batch, int* __restrict__ center,
                         int n_nodes, int n_graphs) {
    int g = blockIdx.x * blockDim.x + threadIdx.x;
    if (g >= n_graphs) return;
    int lo = 0, hi = n_nodes;
    while (lo < hi) {
        int mid = (lo + hi) >> 1;
        if (batch[mid] < g) lo = mid + 1;
        else hi = mid;
    }
    center[g] = lo;
}

// ---------------- readout: one wave per graph ----------------
__global__ void k_readout(const float* __restrict__ x, const int* __restrict__ center,
                          const float* __restrict__ w1, const float* __restrict__ b1,
                          const float* __restrict__ w2, const float* __restrict__ b2,
                          float* __restrict__ out, int n_nodes, int n_graphs) {
    __shared__ float h[HID];
    int g = blockIdx.x;
    if (g >= n_graphs) return;
    int lane = threadIdx.x;  // 64
    int c = center[g];
    int r0 = min(c, n_nodes - 1);      // JAX index clamp semantics
    int r1 = min(c + 1, n_nodes - 1);
    float2 a = ((const float2*)(x + (size_t)r0 * HID))[lane];
    float2 b = ((const float2*)(x + (size_t)r1 * HID))[lane];
    h[2 * lane] = a.x * b.x;
    h[2 * lane + 1] = a.y * b.y;
    __syncthreads();
    int d0 = 2 * lane;
    float acc0 = b1[d0], acc1 = b1[d0 + 1];
    const float4* w1a = (const float4*)(w1 + (size_t)d0 * HID);
    const float4* w1b = (const float4*)(w1 + (size_t)(d0 + 1) * HID);
#pragma unroll 8
    for (int k4 = 0; k4 < HID / 4; ++k4) {
        float4 hv = *(const float4*)&h[k4 * 4];
        float4 wa = w1a[k4];
        float4 wb = w1b[k4];
        acc0 += hv.x * wa.x + hv.y * wa.y + hv.z * wa.z + hv.w * wa.w;
        acc1 += hv.x * wb.x + hv.y * wb.y + hv.z * wb.z + hv.w * wb.w;
    }
    float p = fmaxf(acc0, 0.f) * w2[d0] + fmaxf(acc1, 0.f) * w2[d0 + 1];
#pragma unroll
    for (int off = 32; off > 0; off >>= 1) p += __shfl_down(p, off);
    if (lane == 0) out[g] = p + b2[0];
}

extern "C" void kernel_launch(void* const* d_in, const int* in_sizes, int n_in,
                              void* d_out, int out_size, void* d_ws, size_t ws_size,
                              hipStream_t stream) {
    const int* z = (const int*)d_in[0];
    const int* edge_index = (const int*)d_in[1];
    const int* batch = (const int*)d_in[2];
    const float* z_emb = (const float*)d_in[4];
    const float* Wl = (const float*)d_in[5];
    const float* bl = (const float*)d_in[6];
    const float* Wr = (const float*)d_in[7];
    const float* lin1_w = (const float*)d_in[8];
    const float* lin1_b = (const float*)d_in[9];
    const float* lin2_w = (const float*)d_in[10];
    const float* lin2_b = (const float*)d_in[11];
    float* out = (float*)d_out;

    int n_nodes = in_sizes[0];
    int n_edges = in_sizes[1] / 2;
    int n_graphs = out_size;  // output is [n_graphs, 1]

    const int* e_src = edge_index;
    const int* e_dst = edge_index + n_edges;

    char* p = (char*)d_ws;
    auto alloc = [&](size_t bytes) {
        char* r = p;
        p += (bytes + 511) & ~(size_t)511;
        return r;
    };
    float* x      = (float*)alloc((size_t)n_nodes * HID * 4);
    float* agg    = (float*)alloc((size_t)n_nodes * HID * 4);
    int*   deg    = (int*)alloc((size_t)n_nodes * 4);
    float* deginv = (float*)alloc((size_t)n_nodes * 4);
    int*   rowptr = (int*)alloc((size_t)(n_nodes + 1) * 4);
    int*   cursor = (int*)alloc((size_t)n_nodes * 4);
    int*   csr    = (int*)alloc((size_t)n_edges * 4);
    int*   parts  = (int*)alloc(64 * 4);
    int*   center = (int*)alloc((size_t)n_graphs * 4);
    float* wcatT  = (float*)alloc((size_t)3 * 2 * HID * HID * 4);

    hipMemsetAsync(deg, 0, (size_t)n_nodes * 4, stream);
    hipMemsetAsync(cursor, 0, (size_t)n_nodes * 4, stream);

    k_wt<<<(3 * 2 * HID * HID + 255) / 256, 256, 0, stream>>>(Wl, Wr, wcatT);
    k_embed<<<(n_nodes * (HID / 4) + 255) / 256, 256, 0, stream>>>(z, z_emb, x, n_nodes);
    k_count<<<(n_edges + 255) / 256, 256, 0, stream>>>(e_dst, deg, n_edges);

    int nchunks = (n_nodes + SCAN_CHUNK - 1) / SCAN_CHUNK;
    k_scan1<<<nchunks, 256, 0, stream>>>(deg, parts, n_nodes);
    k_scan2<<<1, 64, 0, stream>>>(parts, nchunks);
    k_scan3<<<nchunks, 256, 0, stream>>>(deg, parts, rowptr, deginv, n_nodes);
    k_fill<<<(n_edges + 255) / 256, 256, 0, stream>>>(e_src, e_dst, rowptr, cursor, csr, n_edges);

    int agg_blocks = (n_nodes * 64 + 255) / 256;
    int gemm_blocks = (n_nodes + NT - 1) / NT;
    for (int layer = 0; layer < 3; ++layer) {
        k_agg<<<agg_blocks, 256, 0, stream>>>(x, agg, rowptr, csr, deginv, n_nodes);
        k_gemm<<<gemm_blocks, 256, 0, stream>>>(agg, x,
                                                wcatT + (size_t)layer * 2 * HID * HID,
                                                bl + (size_t)layer * HID,
                                                n_nodes, layer < 2 ? 1 : 0);
    }
    k_center<<<(n_graphs + 255) / 256, 256, 0, stream>>>(batch, center, n_nodes, n_graphs);
    k_readout<<<n_graphs, 64, 0, stream>>>(x, center, lin1_w, lin1_b, lin2_w, lin2_b,
                                           out, n_nodes, n_graphs);
}

// Round 2
// 707.100 us; speedup vs baseline: 1.2875x; 1.2875x over previous
//
#include <hip/hip_runtime.h>
#include <hip/hip_bf16.h>
#include <cstdint>

#define HID 128
#define GM 128          // nodes per GEMM block
#define SCAN_CHUNK 2048

typedef __attribute__((ext_vector_type(8))) short bf16x8;
typedef __attribute__((ext_vector_type(4))) float f32x4;

__device__ __forceinline__ unsigned short f2bf(float f) {
    union { __hip_bfloat16 h; unsigned short u; } c;
    c.h = __float2bfloat16(f);
    return c.u;
}
__device__ __forceinline__ float bf2f(unsigned short u) {
    union { unsigned int i; float f; } c;
    c.i = ((unsigned int)u) << 16;
    return c.f;
}
__device__ __forceinline__ unsigned int pack2(unsigned short a, unsigned short b) {
    return (unsigned int)a | ((unsigned int)b << 16);
}
__device__ __forceinline__ bf16x8 ld_frag(const unsigned int* p) {
    union { uint4 u; bf16x8 f; } c;
    c.u = *(const uint4*)p;
    return c.f;
}

// ---------------- embedding gather ----------------
__global__ void k_embed(const int* __restrict__ z, const float* __restrict__ z_emb,
                        float* __restrict__ x, int n_nodes) {
    int idx = blockIdx.x * blockDim.x + threadIdx.x;
    int total = n_nodes * (HID / 4);
    if (idx >= total) return;
    int node = idx >> 5;  // HID/4 = 32 float4 per row
    int j = idx & 31;
    ((float4*)x)[idx] = ((const float4*)z_emb)[(size_t)z[node] * 32 + j];
}

// ---------------- degree count ----------------
__global__ void k_count(const int* __restrict__ dst, int* __restrict__ deg, int n_edges) {
    int e = blockIdx.x * blockDim.x + threadIdx.x;
    if (e < n_edges) atomicAdd(&deg[dst[e]], 1);
}

// ---------------- 3-pass exclusive scan of degrees -> rowptr ----------------
__global__ void k_scan1(const int* __restrict__ deg, int* __restrict__ partials, int n) {
    __shared__ int sm[256];
    int t = threadIdx.x;
    int base = blockIdx.x * SCAN_CHUNK + t * 8;
    int s = 0;
#pragma unroll
    for (int j = 0; j < 8; ++j) { int i = base + j; if (i < n) s += deg[i]; }
    sm[t] = s;
    __syncthreads();
    for (int off = 128; off > 0; off >>= 1) {
        if (t < off) sm[t] += sm[t + off];
        __syncthreads();
    }
    if (t == 0) partials[blockIdx.x] = sm[0];
}

__global__ void k_scan2(int* partials, int nchunks) {
    int lane = threadIdx.x;  // blockDim = 64, nchunks <= 64
    int v = (lane < nchunks) ? partials[lane] : 0;
#pragma unroll
    for (int off = 1; off < 64; off <<= 1) {
        int u = __shfl_up(v, off);
        if (lane >= off) v += u;
    }
    int ex = __shfl_up(v, 1);
    if (lane == 0) ex = 0;
    if (lane < nchunks) partials[lane] = ex;
}

__global__ void k_scan3(const int* __restrict__ deg, const int* __restrict__ partials,
                        int* __restrict__ rowptr, float* __restrict__ deg_inv, int n) {
    __shared__ int wtot[4];
    int t = threadIdx.x;
    int lane = t & 63, wv = t >> 6;
    int base = blockIdx.x * SCAN_CHUNK + t * 8;
    int v[8];
    int ts = 0;
#pragma unroll
    for (int j = 0; j < 8; ++j) { int i = base + j; v[j] = (i < n) ? deg[i] : 0; ts += v[j]; }
    int incl = ts;
#pragma unroll
    for (int off = 1; off < 64; off <<= 1) {
        int u = __shfl_up(incl, off);
        if (lane >= off) incl += u;
    }
    if (lane == 63) wtot[wv] = incl;
    __syncthreads();
    int woff = 0;
    for (int w = 0; w < wv; ++w) woff += wtot[w];
    int run = partials[blockIdx.x] + woff + (incl - ts);
#pragma unroll
    for (int j = 0; j < 8; ++j) {
        int i = base + j;
        run += v[j];
        if (i < n) {
            rowptr[i + 1] = run;
            deg_inv[i] = 1.0f / fmaxf((float)v[j], 1.0f);
        }
    }
    if (blockIdx.x == 0 && t == 0) rowptr[0] = 0;
}

// ---------------- CSR fill ----------------
__global__ void k_fill(const int* __restrict__ src, const int* __restrict__ dst,
                       const int* __restrict__ rowptr, int* __restrict__ cursor,
                       int* __restrict__ csr_src, int n_edges) {
    int e = blockIdx.x * blockDim.x + threadIdx.x;
    if (e >= n_edges) return;
    int d = dst[e];
    int pos = atomicAdd(&cursor[d], 1);
    csr_src[rowptr[d] + pos] = src[e];
}

// ---------------- mean aggregation: one wave per node, 8 rows in flight ----------------
__global__ __launch_bounds__(256) void k_agg(const float* __restrict__ x, float* __restrict__ agg,
                      const int* __restrict__ rowptr, const int* __restrict__ csr_src,
                      const float* __restrict__ deg_inv, int n_nodes) {
    int wid = blockIdx.x * (blockDim.x >> 6) + (threadIdx.x >> 6);
    int lane = threadIdx.x & 63;
    if (wid >= n_nodes) return;
    int s = rowptr[wid], e = rowptr[wid + 1];
    int half = lane >> 5;   // half-wave 0: even edge slots, 1: odd edge slots
    int col = lane & 31;    // float4 column within the row
    const float4* xv = (const float4*)x;
    float4 a0 = {0.f,0.f,0.f,0.f}, a1 = {0.f,0.f,0.f,0.f};
    float4 a2 = {0.f,0.f,0.f,0.f}, a3 = {0.f,0.f,0.f,0.f};
    int i = s + half;
    for (; i + 6 < e; i += 8) {   // 4 rows in flight per half-wave
        int s0 = csr_src[i];
        int s1 = csr_src[i + 2];
        int s2 = csr_src[i + 4];
        int s3 = csr_src[i + 6];
        float4 v0 = xv[(size_t)s0 * 32 + col];
        float4 v1 = xv[(size_t)s1 * 32 + col];
        float4 v2 = xv[(size_t)s2 * 32 + col];
        float4 v3 = xv[(size_t)s3 * 32 + col];
        a0.x += v0.x; a0.y += v0.y; a0.z += v0.z; a0.w += v0.w;
        a1.x += v1.x; a1.y += v1.y; a1.z += v1.z; a1.w += v1.w;
        a2.x += v2.x; a2.y += v2.y; a2.z += v2.z; a2.w += v2.w;
        a3.x += v3.x; a3.y += v3.y; a3.z += v3.z; a3.w += v3.w;
    }
    for (; i < e; i += 2) {
        int s0 = csr_src[i];
        float4 v0 = xv[(size_t)s0 * 32 + col];
        a0.x += v0.x; a0.y += v0.y; a0.z += v0.z; a0.w += v0.w;
    }
    a0.x += a1.x + a2.x + a3.x;
    a0.y += a1.y + a2.y + a3.y;
    a0.z += a1.z + a2.z + a3.z;
    a0.w += a1.w + a2.w + a3.w;
    // combine the two half-waves
    a0.x += __shfl_xor(a0.x, 32);
    a0.y += __shfl_xor(a0.y, 32);
    a0.z += __shfl_xor(a0.z, 32);
    a0.w += __shfl_xor(a0.w, 32);
    if (half == 0) {
        float di = deg_inv[wid];
        float4 o = make_float4(a0.x * di, a0.y * di, a0.z * di, a0.w * di);
        ((float4*)agg)[(size_t)wid * 32 + col] = o;
    }
}

// ---------------- split W into bf16 hi/lo planes, layout [l][d][k=256] ----------------
__global__ void k_wsplit(const float* __restrict__ Wl, const float* __restrict__ Wr,
                         unsigned short* __restrict__ wh, unsigned short* __restrict__ wlo) {
    int idx = blockIdx.x * blockDim.x + threadIdx.x;
    if (idx >= 3 * HID * 2 * HID) return;
    int l = idx / (HID * 2 * HID);
    int r = idx - l * (HID * 2 * HID);
    int d = r >> 8;        // 0..127
    int k = r & 255;       // 0..255
    float v = (k < HID) ? Wl[((size_t)l * HID + d) * HID + k]
                        : Wr[((size_t)l * HID + d) * HID + (k - HID)];
    unsigned short h = f2bf(v);
    unsigned short lo = f2bf(v - bf2f(h));
    wh[idx] = h;
    wlo[idx] = lo;
}

// ---------------- fused layer GEMM via split-bf16 MFMA ----------------
// x[node][d] = relu?( sum_k [agg|x][node][k] * W[d][k] + bias[d] ), in place.
__global__ __launch_bounds__(256) void k_gemm(const float* __restrict__ agg,
                                              float* __restrict__ x,
                                              const unsigned short* __restrict__ wh,
                                              const unsigned short* __restrict__ wlo,
                                              const float* __restrict__ bias,
                                              int n_nodes, int do_relu) {
    // u32 LDS tiles: [row][16 u32] = [row][32 bf16], 64B rows, 16B-aligned frag reads
    __shared__ unsigned int sAh[GM * 16], sAl[GM * 16];
    __shared__ unsigned int sBh[HID * 16], sBl[HID * 16];
    int t = threadIdx.x;
    int node0 = blockIdx.x * GM;
    int wv = t >> 6, lane = t & 63;
    int lrow = lane & 15, lk = lane >> 4;

    f32x4 acc[2][8];
#pragma unroll
    for (int m = 0; m < 2; ++m)
#pragma unroll
        for (int n = 0; n < 8; ++n) acc[m][n] = (f32x4){0.f, 0.f, 0.f, 0.f};

    int srow = t >> 2;      // 0..63 (+64 for rr=1)
    int sq = t & 3;         // quarter of the 32-k row

    for (int c = 0; c < 8; ++c) {
        const float* srcp = (c < 4) ? agg : x;
        int kbase = (c & 3) * 32;
        int kb = c * 32;
        // --- stage A: 128 rows x 32 k, fp32 -> split bf16 hi/lo ---
#pragma unroll
        for (int rr = 0; rr < 2; ++rr) {
            int row = srow + rr * 64;
            int node = node0 + row;
            float f[8];
            if (node < n_nodes) {
                const float4* rp = (const float4*)(srcp + (size_t)node * HID + kbase + sq * 8);
                float4 v0 = rp[0], v1 = rp[1];
                f[0]=v0.x; f[1]=v0.y; f[2]=v0.z; f[3]=v0.w;
                f[4]=v1.x; f[5]=v1.y; f[6]=v1.z; f[7]=v1.w;
            } else {
#pragma unroll
                for (int j = 0; j < 8; ++j) f[j] = 0.f;
            }
            unsigned int h[4], l[4];
#pragma unroll
            for (int j = 0; j < 4; ++j) {
                unsigned short h0 = f2bf(f[2*j]), h1 = f2bf(f[2*j+1]);
                unsigned short l0 = f2bf(f[2*j] - bf2f(h0));
                unsigned short l1 = f2bf(f[2*j+1] - bf2f(h1));
                h[j] = pack2(h0, h1);
                l[j] = pack2(l0, l1);
            }
            unsigned int base = row * 16 + sq * 4;
            *(uint4*)&sAh[base] = make_uint4(h[0], h[1], h[2], h[3]);
            *(uint4*)&sAl[base] = make_uint4(l[0], l[1], l[2], l[3]);
        }
        // --- stage B: 128 d-rows x 32 k, bf16 copy ---
#pragma unroll
        for (int rr = 0; rr < 2; ++rr) {
            int d = srow + rr * 64;
            size_t go = (size_t)d * 256 + kb + sq * 8;
            uint4 vh = *(const uint4*)(wh + go);
            uint4 vl = *(const uint4*)(wlo + go);
            unsigned int base = d * 16 + sq * 4;
            *(uint4*)&sBh[base] = vh;
            *(uint4*)&sBl[base] = vl;
        }
        __syncthreads();
        // --- compute: 2 M-tiles x 8 N-tiles x 3 split products ---
        bf16x8 ah0, al0, ah1, al1;
        {
            unsigned int a0 = (unsigned)(wv * 32 + lrow) * 16 + lk * 4;
            unsigned int a1 = (unsigned)(wv * 32 + 16 + lrow) * 16 + lk * 4;
            ah0 = ld_frag(&sAh[a0]); al0 = ld_frag(&sAl[a0]);
            ah1 = ld_frag(&sAh[a1]); al1 = ld_frag(&sAl[a1]);
        }
#pragma unroll
        for (int n = 0; n < 8; ++n) {
            unsigned int b = (unsigned)(n * 16 + lrow) * 16 + lk * 4;
            bf16x8 bh = ld_frag(&sBh[b]);
            bf16x8 bl = ld_frag(&sBl[b]);
            acc[0][n] = __builtin_amdgcn_mfma_f32_16x16x32_bf16(ah0, bh, acc[0][n], 0, 0, 0);
            acc[0][n] = __builtin_amdgcn_mfma_f32_16x16x32_bf16(al0, bh, acc[0][n], 0, 0, 0);
            acc[0][n] = __builtin_amdgcn_mfma_f32_16x16x32_bf16(ah0, bl, acc[0][n], 0, 0, 0);
            acc[1][n] = __builtin_amdgcn_mfma_f32_16x16x32_bf16(ah1, bh, acc[1][n], 0, 0, 0);
            acc[1][n] = __builtin_amdgcn_mfma_f32_16x16x32_bf16(al1, bh, acc[1][n], 0, 0, 0);
            acc[1][n] = __builtin_amdgcn_mfma_f32_16x16x32_bf16(ah1, bl, acc[1][n], 0, 0, 0);
        }
        __syncthreads();
    }
    // --- epilogue: bias + relu + store (D: col=lane&15, row=(lane>>4)*4+reg) ---
#pragma unroll
    for (int m = 0; m < 2; ++m) {
        int rbase = node0 + wv * 32 + m * 16 + lk * 4;
#pragma unroll
        for (int n = 0; n < 8; ++n) {
            int colb = n * 16 + lrow;
            float bb = bias[colb];
#pragma unroll
            for (int r = 0; r < 4; ++r) {
                int row = rbase + r;
                if (row < n_nodes) {
                    float v = acc[m][n][r] + bb;
                    if (do_relu) v = fmaxf(v, 0.f);
                    x[(size_t)row * HID + colb] = v;
                }
            }
        }
    }
}

// ---------------- center = lower_bound(batch, g) ----------------
__global__ void k_center(const int* __restrict__ batch, int* __restrict__ center,
                         int n_nodes, int n_graphs) {
    int g = blockIdx.x * blockDim.x + threadIdx.x;
    if (g >= n_graphs) return;
    int lo = 0, hi = n_nodes;
    while (lo < hi) {
        int mid = (lo + hi) >> 1;
        if (batch[mid] < g) lo = mid + 1;
        else hi = mid;
    }
    center[g] = lo;
}

// ---------------- readout: one wave per graph ----------------
__global__ void k_readout(const float* __restrict__ x, const int* __restrict__ center,
                          const float* __restrict__ w1, const float* __restrict__ b1,
                          const float* __restrict__ w2, const float* __restrict__ b2,
                          float* __restrict__ out, int n_nodes, int n_graphs) {
    __shared__ float h[HID];
    int g = blockIdx.x;
    if (g >= n_graphs) return;
    int lane = threadIdx.x;  // 64
    int c = center[g];
    int r0 = min(c, n_nodes - 1);      // JAX index clamp semantics
    int r1 = min(c + 1, n_nodes - 1);
    float2 a = ((const float2*)(x + (size_t)r0 * HID))[lane];
    float2 b = ((const float2*)(x + (size_t)r1 * HID))[lane];
    h[2 * lane] = a.x * b.x;
    h[2 * lane + 1] = a.y * b.y;
    __syncthreads();
    int d0 = 2 * lane;
    float acc0 = b1[d0], acc1 = b1[d0 + 1];
    const float4* w1a = (const float4*)(w1 + (size_t)d0 * HID);
    const float4* w1b = (const float4*)(w1 + (size_t)(d0 + 1) * HID);
#pragma unroll 8
    for (int k4 = 0; k4 < HID / 4; ++k4) {
        float4 hv = *(const float4*)&h[k4 * 4];
        float4 wa = w1a[k4];
        float4 wb = w1b[k4];
        acc0 += hv.x * wa.x + hv.y * wa.y + hv.z * wa.z + hv.w * wa.w;
        acc1 += hv.x * wb.x + hv.y * wb.y + hv.z * wb.z + hv.w * wb.w;
    }
    float p = fmaxf(acc0, 0.f) * w2[d0] + fmaxf(acc1, 0.f) * w2[d0 + 1];
#pragma unroll
    for (int off = 32; off > 0; off >>= 1) p += __shfl_down(p, off);
    if (lane == 0) out[g] = p + b2[0];
}

extern "C" void kernel_launch(void* const* d_in, const int* in_sizes, int n_in,
                              void* d_out, int out_size, void* d_ws, size_t ws_size,
                              hipStream_t stream) {
    const int* z = (const int*)d_in[0];
    const int* edge_index = (const int*)d_in[1];
    const int* batch = (const int*)d_in[2];
    const float* z_emb = (const float*)d_in[4];
    const float* Wl = (const float*)d_in[5];
    const float* bl = (const float*)d_in[6];
    const float* Wr = (const float*)d_in[7];
    const float* lin1_w = (const float*)d_in[8];
    const float* lin1_b = (const float*)d_in[9];
    const float* lin2_w = (const float*)d_in[10];
    const float* lin2_b = (const float*)d_in[11];
    float* out = (float*)d_out;

    int n_nodes = in_sizes[0];
    int n_edges = in_sizes[1] / 2;
    int n_graphs = out_size;  // output is [n_graphs, 1]

    const int* e_src = edge_index;
    const int* e_dst = edge_index + n_edges;

    char* p = (char*)d_ws;
    auto alloc = [&](size_t bytes) {
        char* r = p;
        p += (bytes + 511) & ~(size_t)511;
        return r;
    };
    float* x      = (float*)alloc((size_t)n_nodes * HID * 4);
    float* agg    = (float*)alloc((size_t)n_nodes * HID * 4);
    int*   deg    = (int*)alloc((size_t)n_nodes * 4);
    float* deginv = (float*)alloc((size_t)n_nodes * 4);
    int*   rowptr = (int*)alloc((size_t)(n_nodes + 1) * 4);
    int*   cursor = (int*)alloc((size_t)n_nodes * 4);
    int*   csr    = (int*)alloc((size_t)n_edges * 4);
    int*   parts  = (int*)alloc(64 * 4);
    int*   center = (int*)alloc((size_t)n_graphs * 4);
    unsigned short* wh  = (unsigned short*)alloc((size_t)3 * HID * 2 * HID * 2);
    unsigned short* wlo = (unsigned short*)alloc((size_t)3 * HID * 2 * HID * 2);

    hipMemsetAsync(deg, 0, (size_t)n_nodes * 4, stream);
    hipMemsetAsync(cursor, 0, (size_t)n_nodes * 4, stream);

    k_wsplit<<<(3 * HID * 2 * HID + 255) / 256, 256, 0, stream>>>(Wl, Wr, wh, wlo);
    k_embed<<<(n_nodes * (HID / 4) + 255) / 256, 256, 0, stream>>>(z, z_emb, x, n_nodes);
    k_count<<<(n_edges + 255) / 256, 256, 0, stream>>>(e_dst, deg, n_edges);

    int nchunks = (n_nodes + SCAN_CHUNK - 1) / SCAN_CHUNK;
    k_scan1<<<nchunks, 256, 0, stream>>>(deg, parts, n_nodes);
    k_scan2<<<1, 64, 0, stream>>>(parts, nchunks);
    k_scan3<<<nchunks, 256, 0, stream>>>(deg, parts, rowptr, deginv, n_nodes);
    k_fill<<<(n_edges + 255) / 256, 256, 0, stream>>>(e_src, e_dst, rowptr, cursor, csr, n_edges);

    int agg_blocks = (n_nodes * 64 + 255) / 256;
    int gemm_blocks = (n_nodes + GM - 1) / GM;
    for (int layer = 0; layer < 3; ++layer) {
        k_agg<<<agg_blocks, 256, 0, stream>>>(x, agg, rowptr, csr, deginv, n_nodes);
        k_gemm<<<gemm_blocks, 256, 0, stream>>>(agg, x,
                                                wh + (size_t)layer * HID * 2 * HID,
                                                wlo + (size_t)layer * HID * 2 * HID,
                                                bl + (size_t)layer * HID,
                                                n_nodes, layer < 2 ? 1 : 0);
    }
    k_center<<<(n_graphs + 255) / 256, 256, 0, stream>>>(batch, center, n_nodes, n_graphs);
    k_readout<<<n_graphs, 64, 0, stream>>>(x, center, lin1_w, lin1_b, lin2_w, lin2_b,
                                           out, n_nodes, n_graphs);
}